// Round 1
// baseline (492.890 us; speedup 1.0000x reference)
//
#include <hip/hip_runtime.h>
#include <math.h>

#define BB_   2
#define CIN_  256
#define NTOK_ 2048
#define FF_   512
#define COUT_ 256
#define NH_   8
#define DH_   64
#define HW_   128
#define INVT_ (1.0f / 16.0f)
#define BNEPS_ 1e-5f

// ---------------------------------------------------------------------------
// Kernel 1: QKV projection.  Y[b,f,n] = sum_c W[f,c] * x[b,c,n]
// Output layout [b][h][n][d]  (f = h*64 + d) so attention tiles are contiguous.
// Block: 64 f x 128 n tile, 256 threads, each thread 4f x 8n.
// Also zeroes the BN stats buffer (block (0,0,0)) so no memset is needed.
// ---------------------------------------------------------------------------
__global__ __launch_bounds__(256) void qkv_kernel(
    const float* __restrict__ x, const float* __restrict__ WK,
    const float* __restrict__ WQ, const float* __restrict__ WV,
    float* __restrict__ Kb, float* __restrict__ Qb, float* __restrict__ Vb,
    float* __restrict__ stats) {
  __shared__ float Wt[32][68];    // [kc][f], pitch 68: float4-aligned, conflict-free
  __shared__ float Xt[32][128];   // [kc][n]
  const int tid = threadIdx.x;
  const int n0 = blockIdx.x * 128;
  const int f0 = blockIdx.y * 64;
  const int b = blockIdx.z / 3;
  const int which = blockIdx.z % 3;

  if (blockIdx.x == 0 && blockIdx.y == 0 && blockIdx.z == 0) {
    for (int i = tid; i < 2 * COUT_; i += 256) stats[i] = 0.f;
  }

  const float* W = (which == 0) ? WK : (which == 1) ? WQ : WV;
  float* Y = (which == 0) ? Kb : (which == 1) ? Qb : Vb;

  const int tx = tid & 15, ty = tid >> 4;
  float acc[4][8];
#pragma unroll
  for (int a = 0; a < 4; ++a)
#pragma unroll
    for (int q = 0; q < 8; ++q) acc[a][q] = 0.f;

  for (int c0 = 0; c0 < CIN_; c0 += 32) {
    __syncthreads();
    {  // stage W tile (transposed): Wt[kc][f] = W[f0+f][c0+kc]
      const int fr = tid >> 3;
      const int cc = (tid & 7) * 4;
#pragma unroll
      for (int p = 0; p < 2; ++p) {
        const int f = p * 32 + fr;
        const float4 w = *(const float4*)(W + (size_t)(f0 + f) * CIN_ + c0 + cc);
        Wt[cc + 0][f] = w.x; Wt[cc + 1][f] = w.y;
        Wt[cc + 2][f] = w.z; Wt[cc + 3][f] = w.w;
      }
    }
    {  // stage x tile: Xt[kc][n] = x[b][c0+kc][n0+n]
      const int kc = tid >> 3;
      const int nn = (tid & 7) * 16;
      const float* src = x + ((size_t)b * CIN_ + c0 + kc) * NTOK_ + n0 + nn;
#pragma unroll
      for (int q = 0; q < 4; ++q)
        *(float4*)&Xt[kc][nn + q * 4] = *(const float4*)(src + q * 4);
    }
    __syncthreads();
#pragma unroll
    for (int kc = 0; kc < 32; ++kc) {
      const float4 wv = *(const float4*)&Wt[kc][ty * 4];
      float xv[8];
#pragma unroll
      for (int q = 0; q < 8; ++q) xv[q] = Xt[kc][tx + 16 * q];
      const float wa[4] = {wv.x, wv.y, wv.z, wv.w};
#pragma unroll
      for (int a = 0; a < 4; ++a)
#pragma unroll
        for (int q = 0; q < 8; ++q) acc[a][q] = fmaf(wa[a], xv[q], acc[a][q]);
    }
  }
  // store: [b][h][n][d], h = f0/64, d = ty*4+a (f0 is a multiple of 64)
  const int h = f0 >> 6;
  float* base = Y + ((size_t)b * NH_ + h) * (size_t)NTOK_ * DH_;
#pragma unroll
  for (int q = 0; q < 8; ++q) {
    const int n = n0 + tx + 16 * q;
    float4 o;
    o.x = acc[0][q]; o.y = acc[1][q]; o.z = acc[2][q]; o.w = acc[3][q];
    *(float4*)(base + (size_t)n * DH_ + ty * 4) = o;
  }
}

// ---------------------------------------------------------------------------
// Kernel 2: block-causal attention, flash-style.
// Grid: (i-tile 0..31, head 0..7, batch 0..1).  i-tile = 64 rows, all within one
// time step (HW=128), so the causal mask is uniform: allowed j < (t+1)*128.
// S[i,j] = sum_d K[i,d]*Q[j,d]; online softmax over j; O[i,d] += P[i,j]*V[j,d].
// ---------------------------------------------------------------------------
__global__ __launch_bounds__(256) void attn_kernel(
    const float* __restrict__ Kb, const float* __restrict__ Qb,
    const float* __restrict__ Vb, float* __restrict__ Ob) {
  __shared__ float Ksh[64 * 65];  // [i][d]
  __shared__ float Xsh[64 * 65];  // Q then V per j-tile: [j][d]
  __shared__ float Ssh[64 * 65];  // scores/probs [i][j]
  __shared__ float rowM[64], rowL[64], rowC[64];

  const int tid = threadIdx.x;
  const int iblk = blockIdx.x;             // 0..31
  const int h = blockIdx.y, b = blockIdx.z;
  const int i0 = iblk * 64;
  const int it = iblk >> 1;                // time step of this i-tile
  const int njt = (it + 1) * 2;            // allowed 64-wide j tiles
  const size_t base = ((size_t)b * NH_ + h) * (size_t)NTOK_ * DH_;
  const float* Kp = Kb + base;
  const float* Qp = Qb + base;
  const float* Vp = Vb + base;

  // load K tile (4096 contiguous floats)
#pragma unroll
  for (int q = 0; q < 4; ++q) {
    const int e = (tid + q * 256) * 4;
    const int r = e >> 6, c = e & 63;
    const float4 v = *(const float4*)(Kp + (size_t)i0 * DH_ + e);
    Ksh[r * 65 + c + 0] = v.x; Ksh[r * 65 + c + 1] = v.y;
    Ksh[r * 65 + c + 2] = v.z; Ksh[r * 65 + c + 3] = v.w;
  }
  if (tid < 64) { rowM[tid] = -1e30f; rowL[tid] = 0.f; }
  float accO[4][4];
#pragma unroll
  for (int a = 0; a < 4; ++a)
#pragma unroll
    for (int q = 0; q < 4; ++q) accO[a][q] = 0.f;
  const int tx = tid & 15, ty = tid >> 4;
  __syncthreads();

  for (int jt = 0; jt < njt; ++jt) {
    const int j0 = jt * 64;
    // stage Q tile
#pragma unroll
    for (int q = 0; q < 4; ++q) {
      const int e = (tid + q * 256) * 4;
      const int r = e >> 6, c = e & 63;
      const float4 v = *(const float4*)(Qp + (size_t)j0 * DH_ + e);
      Xsh[r * 65 + c + 0] = v.x; Xsh[r * 65 + c + 1] = v.y;
      Xsh[r * 65 + c + 2] = v.z; Xsh[r * 65 + c + 3] = v.w;
    }
    __syncthreads();
    // S-phase: thread computes 4i x 4j raw scores
    {
      float s[4][4];
#pragma unroll
      for (int a = 0; a < 4; ++a)
#pragma unroll
        for (int q = 0; q < 4; ++q) s[a][q] = 0.f;
      for (int d = 0; d < 64; ++d) {
        float kv[4], qv[4];
#pragma unroll
        for (int a = 0; a < 4; ++a) kv[a] = Ksh[(ty * 4 + a) * 65 + d];
#pragma unroll
        for (int q = 0; q < 4; ++q) qv[q] = Xsh[(tx + 16 * q) * 65 + d];
#pragma unroll
        for (int a = 0; a < 4; ++a)
#pragma unroll
          for (int q = 0; q < 4; ++q) s[a][q] = fmaf(kv[a], qv[q], s[a][q]);
      }
#pragma unroll
      for (int a = 0; a < 4; ++a)
#pragma unroll
        for (int q = 0; q < 4; ++q)
          Ssh[(ty * 4 + a) * 65 + tx + 16 * q] = s[a][q];
    }
    __syncthreads();
    // stage V tile into Xsh (Q fully consumed); concurrently softmax by tid<64
#pragma unroll
    for (int q = 0; q < 4; ++q) {
      const int e = (tid + q * 256) * 4;
      const int r = e >> 6, c = e & 63;
      const float4 v = *(const float4*)(Vp + (size_t)j0 * DH_ + e);
      Xsh[r * 65 + c + 0] = v.x; Xsh[r * 65 + c + 1] = v.y;
      Xsh[r * 65 + c + 2] = v.z; Xsh[r * 65 + c + 3] = v.w;
    }
    if (tid < 64) {
      const float mo = rowM[tid];
      float mb = -1e30f;
      for (int j = 0; j < 64; ++j) mb = fmaxf(mb, Ssh[tid * 65 + j]);
      mb *= INVT_;
      const float mn = fmaxf(mo, mb);
      const float corr = __expf(mo - mn);
      float sum = 0.f;
      for (int j = 0; j < 64; ++j) {
        const float p = __expf(Ssh[tid * 65 + j] * INVT_ - mn);
        Ssh[tid * 65 + j] = p;
        sum += p;
      }
      rowM[tid] = mn;
      rowL[tid] = rowL[tid] * corr + sum;
      rowC[tid] = corr;
    }
    __syncthreads();
    // O-phase: rescale + accumulate P*V (thread: 4i x 4d)
#pragma unroll
    for (int a = 0; a < 4; ++a) {
      const float corr = rowC[ty * 4 + a];
#pragma unroll
      for (int q = 0; q < 4; ++q) accO[a][q] *= corr;
    }
    for (int j = 0; j < 64; ++j) {
      float pv[4], vv[4];
#pragma unroll
      for (int a = 0; a < 4; ++a) pv[a] = Ssh[(ty * 4 + a) * 65 + j];
#pragma unroll
      for (int q = 0; q < 4; ++q) vv[q] = Xsh[j * 65 + tx + 16 * q];
#pragma unroll
      for (int a = 0; a < 4; ++a)
#pragma unroll
        for (int q = 0; q < 4; ++q) accO[a][q] = fmaf(pv[a], vv[q], accO[a][q]);
    }
    __syncthreads();
  }

  // epilogue: divide by l, stage [i][d] into Ssh, then coalesced store to
  // Ob[b][f][n] with f = h*64+d, n = i0+i.
#pragma unroll
  for (int a = 0; a < 4; ++a) {
    const float invl = 1.0f / rowL[ty * 4 + a];
#pragma unroll
    for (int q = 0; q < 4; ++q)
      Ssh[(ty * 4 + a) * 65 + tx + 16 * q] = accO[a][q] * invl;
  }
  __syncthreads();
#pragma unroll
  for (int q = 0; q < 4; ++q) {
    const int e = tid + q * 256;  // 0..1023 = 64 d x 16 i-groups
    const int d = e >> 4;
    const int i4 = (e & 15) * 4;
    float4 v;
    v.x = Ssh[(i4 + 0) * 65 + d];
    v.y = Ssh[(i4 + 1) * 65 + d];
    v.z = Ssh[(i4 + 2) * 65 + d];
    v.w = Ssh[(i4 + 3) * 65 + d];
    *(float4*)(Ob + ((size_t)b * FF_ + h * 64 + d) * NTOK_ + i0 + i4) = v;
  }
}

// ---------------------------------------------------------------------------
// Kernel 3: output projection + bias + ReLU + skip -> d_out (pre-BN), and
// per-channel sum / sumsq accumulation for BatchNorm.
// y[b,o,n] = relu(sum_f Wo[o,f]*Vo[b,f,n] + bo[o]) + x[b,o,n]
// ---------------------------------------------------------------------------
__global__ __launch_bounds__(256) void proj_kernel(
    const float* __restrict__ Ob, const float* __restrict__ Wo,
    const float* __restrict__ bo, const float* __restrict__ x,
    float* __restrict__ pre, float* __restrict__ stats) {
  __shared__ float Wt[32][68];  // [kc][o]
  __shared__ float Xt[32][64];  // [kc][n]
  const int tid = threadIdx.x;
  const int n0 = blockIdx.x * 64;
  const int o0 = blockIdx.y * 64;
  const int b = blockIdx.z;
  const int tx = tid & 15, ty = tid >> 4;
  float acc[4][4];
#pragma unroll
  for (int a = 0; a < 4; ++a)
#pragma unroll
    for (int q = 0; q < 4; ++q) acc[a][q] = 0.f;

  for (int f0 = 0; f0 < FF_; f0 += 32) {
    __syncthreads();
    {
      const int orow = tid >> 3;
      const int cc = (tid & 7) * 4;
#pragma unroll
      for (int p = 0; p < 2; ++p) {
        const int o = p * 32 + orow;
        const float4 w = *(const float4*)(Wo + (size_t)(o0 + o) * FF_ + f0 + cc);
        Wt[cc + 0][o] = w.x; Wt[cc + 1][o] = w.y;
        Wt[cc + 2][o] = w.z; Wt[cc + 3][o] = w.w;
      }
    }
    {
      const int kc = tid >> 3;
      const int nn = (tid & 7) * 8;
      const float* src = Ob + ((size_t)b * FF_ + f0 + kc) * NTOK_ + n0 + nn;
#pragma unroll
      for (int q = 0; q < 2; ++q)
        *(float4*)&Xt[kc][nn + q * 4] = *(const float4*)(src + q * 4);
    }
    __syncthreads();
#pragma unroll
    for (int kc = 0; kc < 32; ++kc) {
      const float4 wv = *(const float4*)&Wt[kc][ty * 4];
      float xv[4];
#pragma unroll
      for (int q = 0; q < 4; ++q) xv[q] = Xt[kc][tx + 16 * q];
      const float wa[4] = {wv.x, wv.y, wv.z, wv.w};
#pragma unroll
      for (int a = 0; a < 4; ++a)
#pragma unroll
        for (int q = 0; q < 4; ++q) acc[a][q] = fmaf(wa[a], xv[q], acc[a][q]);
    }
  }
  // epilogue + stats
#pragma unroll
  for (int a = 0; a < 4; ++a) {
    const int o = o0 + ty * 4 + a;
    const float bias = bo[o];
    float s = 0.f, s2 = 0.f;
#pragma unroll
    for (int q = 0; q < 4; ++q) {
      const int n = n0 + tx + 16 * q;
      float v = acc[a][q] + bias;
      v = fmaxf(v, 0.f);
      v += x[((size_t)b * CIN_ + o) * NTOK_ + n];
      pre[((size_t)b * COUT_ + o) * NTOK_ + n] = v;
      s += v;
      s2 += v * v;
    }
#pragma unroll
    for (int off = 1; off < 16; off <<= 1) {
      s += __shfl_down(s, off, 16);
      s2 += __shfl_down(s2, off, 16);
    }
    if (tx == 0) {
      atomicAdd(&stats[o], s);
      atomicAdd(&stats[COUT_ + o], s2);
    }
  }
}

// ---------------------------------------------------------------------------
// Kernel 4: BatchNorm finalize, in place on d_out.
// ---------------------------------------------------------------------------
__global__ __launch_bounds__(256) void bn_kernel(
    float* __restrict__ out, const float* __restrict__ stats,
    const float* __restrict__ gamma, const float* __restrict__ beta) {
  const int idx = blockIdx.x * 256 + threadIdx.x;
  const int e = idx * 4;
  const int c = (e >> 11) & (COUT_ - 1);  // (e / NTOK_) % COUT_
  const float inv = 1.0f / (float)(BB_ * NTOK_);
  const float mean = stats[c] * inv;
  const float var = stats[COUT_ + c] * inv - mean * mean;
  const float sc = rsqrtf(var + BNEPS_) * gamma[c];
  const float bt = beta[c];
  float4 v = *(float4*)(out + e);
  v.x = (v.x - mean) * sc + bt;
  v.y = (v.y - mean) * sc + bt;
  v.z = (v.z - mean) * sc + bt;
  v.w = (v.w - mean) * sc + bt;
  *(float4*)(out + e) = v;
}

extern "C" void kernel_launch(void* const* d_in, const int* in_sizes, int n_in,
                              void* d_out, int out_size, void* d_ws, size_t ws_size,
                              hipStream_t stream) {
  (void)in_sizes; (void)n_in; (void)out_size; (void)ws_size;
  const float* x = (const float*)d_in[0];
  const float* WK = (const float*)d_in[1];
  const float* WQ = (const float*)d_in[2];
  const float* WV = (const float*)d_in[3];
  const float* Wo = (const float*)d_in[4];
  const float* bo = (const float*)d_in[5];
  const float* gamma = (const float*)d_in[6];
  const float* beta = (const float*)d_in[7];
  float* ws = (float*)d_ws;
  const size_t SZ = (size_t)BB_ * FF_ * NTOK_;  // 2,097,152 floats
  float* Kb = ws;
  float* Qb = ws + SZ;
  float* Vb = ws + 2 * SZ;
  float* Obuf = ws + 3 * SZ;
  float* stats = ws + 4 * SZ;  // 512 floats: sum[256], sumsq[256]
  float* out = (float*)d_out;

  qkv_kernel<<<dim3(16, 8, 6), 256, 0, stream>>>(x, WK, WQ, WV, Kb, Qb, Vb, stats);
  attn_kernel<<<dim3(32, 8, 2), 256, 0, stream>>>(Kb, Qb, Vb, Obuf);
  proj_kernel<<<dim3(32, 4, 2), 256, 0, stream>>>(Obuf, Wo, bo, x, out, stats);
  bn_kernel<<<1024, 256, 0, stream>>>(out, stats, gamma, beta);
}

// Round 2
// 231.022 us; speedup vs baseline: 2.1335x; 2.1335x over previous
//
#include <hip/hip_runtime.h>
#include <math.h>

#define BB_   2
#define CIN_  256
#define NTOK_ 2048
#define FF_   512
#define COUT_ 256
#define NH_   8
#define DH_   64
#define HW_   128
#define INVT_ (1.0f / 16.0f)
#define BNEPS_ 1e-5f
#define SCALE_LOG2_ 0.09016844005556021f  /* log2(e)/16 */

typedef __attribute__((ext_vector_type(8))) short short8;
typedef __attribute__((ext_vector_type(4))) float f32x4;

__device__ inline unsigned short f2bf(float f) {
  union { float f; unsigned u; } v; v.f = f;
  unsigned r = (v.u + 0x7FFF + ((v.u >> 16) & 1)) >> 16;  // RNE
  return (unsigned short)r;
}

// ---------------------------------------------------------------------------
// Kernel 1: QKV projection (fp32 accumulate, bf16 output).
// K,Q layout [b][h][n][d] bf16; V layout [b][h][d][n] bf16 (transposed so the
// attention PV B-operand stages contiguously). Also zeroes BN stats.
// ---------------------------------------------------------------------------
__global__ __launch_bounds__(256) void qkv_kernel(
    const float* __restrict__ x, const float* __restrict__ WK,
    const float* __restrict__ WQ, const float* __restrict__ WV,
    unsigned short* __restrict__ Kb, unsigned short* __restrict__ Qb,
    unsigned short* __restrict__ Vt, float* __restrict__ stats) {
  __shared__ float Wt[32][68];
  __shared__ float Xt[32][128];
  const int tid = threadIdx.x;
  const int n0 = blockIdx.x * 128;
  const int f0 = blockIdx.y * 64;
  const int b = blockIdx.z / 3;
  const int which = blockIdx.z % 3;

  if (blockIdx.x == 0 && blockIdx.y == 0 && blockIdx.z == 0) {
    for (int i = tid; i < 2 * COUT_; i += 256) stats[i] = 0.f;
  }

  const float* W = (which == 0) ? WK : (which == 1) ? WQ : WV;

  const int tx = tid & 15, ty = tid >> 4;
  float acc[4][8];
#pragma unroll
  for (int a = 0; a < 4; ++a)
#pragma unroll
    for (int q = 0; q < 8; ++q) acc[a][q] = 0.f;

  for (int c0 = 0; c0 < CIN_; c0 += 32) {
    __syncthreads();
    {
      const int fr = tid >> 3;
      const int cc = (tid & 7) * 4;
#pragma unroll
      for (int p = 0; p < 2; ++p) {
        const int f = p * 32 + fr;
        const float4 w = *(const float4*)(W + (size_t)(f0 + f) * CIN_ + c0 + cc);
        Wt[cc + 0][f] = w.x; Wt[cc + 1][f] = w.y;
        Wt[cc + 2][f] = w.z; Wt[cc + 3][f] = w.w;
      }
    }
    {
      const int kc = tid >> 3;
      const int nn = (tid & 7) * 16;
      const float* src = x + ((size_t)b * CIN_ + c0 + kc) * NTOK_ + n0 + nn;
#pragma unroll
      for (int q = 0; q < 4; ++q)
        *(float4*)&Xt[kc][nn + q * 4] = *(const float4*)(src + q * 4);
    }
    __syncthreads();
#pragma unroll
    for (int kc = 0; kc < 32; ++kc) {
      const float4 wv = *(const float4*)&Wt[kc][ty * 4];
      float xv[8];
#pragma unroll
      for (int q = 0; q < 8; ++q) xv[q] = Xt[kc][tx + 16 * q];
      const float wa[4] = {wv.x, wv.y, wv.z, wv.w};
#pragma unroll
      for (int a = 0; a < 4; ++a)
#pragma unroll
        for (int q = 0; q < 8; ++q) acc[a][q] = fmaf(wa[a], xv[q], acc[a][q]);
    }
  }
  const int h = f0 >> 6;
  const size_t bh = ((size_t)b * NH_ + h);
  if (which == 2) {
    // V transposed: Vt[b][h][d][n]
    unsigned short* base = Vt + bh * (size_t)DH_ * NTOK_;
#pragma unroll
    for (int a = 0; a < 4; ++a) {
      const int d = ty * 4 + a;
#pragma unroll
      for (int q = 0; q < 8; ++q)
        base[(size_t)d * NTOK_ + n0 + tx + 16 * q] = f2bf(acc[a][q]);
    }
  } else {
    unsigned short* base = ((which == 0) ? Kb : Qb) + bh * (size_t)NTOK_ * DH_;
#pragma unroll
    for (int q = 0; q < 8; ++q) {
      const int n = n0 + tx + 16 * q;
      ushort4 o;
      o.x = f2bf(acc[0][q]); o.y = f2bf(acc[1][q]);
      o.z = f2bf(acc[2][q]); o.w = f2bf(acc[3][q]);
      *(ushort4*)(base + (size_t)n * DH_ + ty * 4) = o;
    }
  }
}

// ---------------------------------------------------------------------------
// Kernel 2: block-causal attention via MFMA (bf16 in, fp32 accum).
// One block = 64 output rows (i). 4 waves, 16 rows each. Flash-style online
// softmax in registers. Block-causal mask is tile-uniform: njt=(t+1)*2.
// Block-id ordering pairs heavy tiles with light ones (constant-sum pairs).
// ---------------------------------------------------------------------------
__global__ __launch_bounds__(256) void attn_kernel(
    const unsigned short* __restrict__ Kb, const unsigned short* __restrict__ Qb,
    const unsigned short* __restrict__ Vt, float* __restrict__ Ob) {
  // LDS: pitch 72 bf16 (144 B): b128 frag reads hit the 8-phase minimum.
  __shared__ __align__(16) char smem[36864];
  unsigned short* Ksh = (unsigned short*)smem;            // [i][d]  64x72
  unsigned short* Qsh = (unsigned short*)(smem + 9216);   // [j][d]  64x72
  unsigned short* Vsh = (unsigned short*)(smem + 18432);  // [d][j]  64x72
  unsigned short* Psh = (unsigned short*)(smem + 27648);  // [i][j]  64x72

  const int tid = threadIdx.x;
  const int lane = tid & 63;
  const int w = tid >> 6;      // wave 0..3, owns i-rows [16w,16w+16)
  const int lx = lane & 15;
  const int q = lane >> 4;

  // balanced block->tile mapping: pair iblk (31-u) with u
  const int bid = blockIdx.x;  // 0..511
  int iblk;
  if (bid < 256) iblk = 31 - (bid >> 4);
  else           iblk = (bid - 256) >> 4;
  const int sub_bh = bid & 15;
  const int h = sub_bh & 7, b = sub_bh >> 3;
  const int i0 = iblk * 64;
  const int njt = ((iblk >> 1) + 1) * 2;

  const size_t bh = (size_t)b * NH_ + h;
  const unsigned short* Kg = Kb + bh * (size_t)NTOK_ * DH_ + (size_t)i0 * DH_;
  const unsigned short* Qg = Qb + bh * (size_t)NTOK_ * DH_;
  const unsigned short* Vg = Vt + bh * (size_t)DH_ * NTOK_;

  // stage K tile (8 KB)
#pragma unroll
  for (int r = 0; r < 2; ++r) {
    const int c = tid + r * 256;
    const int row = c >> 3, off = (c & 7) * 8;
    *(uint4*)(Ksh + row * 72 + off) = *(const uint4*)(Kg + row * 64 + off);
  }
  __syncthreads();

  // hoist K A-fragments for the whole j-loop: m = lx -> row 16w+lx
  const short8 aK0 = *(const short8*)(Ksh + (16 * w + lx) * 72 + q * 8);
  const short8 aK1 = *(const short8*)(Ksh + (16 * w + lx) * 72 + 32 + q * 8);

  f32x4 o[4];   // O accum: [d-subtile][reg], C-layout rows = q*4+reg
#pragma unroll
  for (int s = 0; s < 4; ++s) o[s] = (f32x4){0.f, 0.f, 0.f, 0.f};
  float m_r[4] = {-1e30f, -1e30f, -1e30f, -1e30f};
  float l_r[4] = {0.f, 0.f, 0.f, 0.f};

  for (int jt = 0; jt < njt; ++jt) {
    const int j0 = jt * 64;
    __syncthreads();  // previous iteration's LDS reads complete
    // stage Q[j][d] and V[d][j] tiles (8 KB each)
#pragma unroll
    for (int r = 0; r < 2; ++r) {
      const int c = tid + r * 256;
      const int row = c >> 3, off = (c & 7) * 8;
      *(uint4*)(Qsh + row * 72 + off) = *(const uint4*)(Qg + (size_t)(j0 + row) * 64 + off);
      *(uint4*)(Vsh + row * 72 + off) = *(const uint4*)(Vg + (size_t)row * NTOK_ + j0 + off);
    }
    __syncthreads();

    // S-phase: S[16i x 64j] per wave, 8 MFMAs
    f32x4 sa[4];
#pragma unroll
    for (int s = 0; s < 4; ++s) {
      sa[s] = (f32x4){0.f, 0.f, 0.f, 0.f};
      const short8 b0 = *(const short8*)(Qsh + (16 * s + lx) * 72 + q * 8);
      const short8 b1 = *(const short8*)(Qsh + (16 * s + lx) * 72 + 32 + q * 8);
      sa[s] = __builtin_amdgcn_mfma_f32_16x16x32_bf16(aK0, b0, sa[s], 0, 0, 0);
      sa[s] = __builtin_amdgcn_mfma_f32_16x16x32_bf16(aK1, b1, sa[s], 0, 0, 0);
    }

    // online softmax in registers (exp2 domain), rows = q*4+reg
    float vmax[4];
#pragma unroll
    for (int r = 0; r < 4; ++r) {
      float m0 = fmaxf(fmaxf(sa[0][r], sa[1][r]), fmaxf(sa[2][r], sa[3][r]));
      m0 *= SCALE_LOG2_;
#pragma unroll
      for (int off = 1; off < 16; off <<= 1)
        m0 = fmaxf(m0, __shfl_xor(m0, off));
      vmax[r] = m0;
    }
    float corr[4], rs[4];
#pragma unroll
    for (int r = 0; r < 4; ++r) {
      const float mn = fmaxf(m_r[r], vmax[r]);
      corr[r] = __builtin_amdgcn_exp2f(m_r[r] - mn);
      m_r[r] = mn;
      rs[r] = 0.f;
    }
    unsigned short pbf[4][4];
#pragma unroll
    for (int s = 0; s < 4; ++s)
#pragma unroll
      for (int r = 0; r < 4; ++r) {
        const float p = __builtin_amdgcn_exp2f(sa[s][r] * SCALE_LOG2_ - m_r[r]);
        pbf[s][r] = f2bf(p);
        rs[r] += p;
      }
#pragma unroll
    for (int r = 0; r < 4; ++r) {
#pragma unroll
      for (int off = 1; off < 16; off <<= 1) rs[r] += __shfl_xor(rs[r], off);
      l_r[r] = l_r[r] * corr[r] + rs[r];
    }
    // rescale O, write P (wave-private rows of Psh)
#pragma unroll
    for (int s = 0; s < 4; ++s) {
      const f32x4 cv = {corr[0], corr[1], corr[2], corr[3]};
      o[s] *= cv;
#pragma unroll
      for (int r = 0; r < 4; ++r)
        Psh[(16 * w + q * 4 + r) * 72 + 16 * s + lx] = pbf[s][r];
    }
    asm volatile("s_waitcnt lgkmcnt(0)" ::: "memory");  // own-wave P visible

    // PV-phase: O[16i x 64d] += P[16 x 64] * V[64 x 64], 8 MFMAs
    const short8 pa0 = *(const short8*)(Psh + (16 * w + lx) * 72 + q * 8);
    const short8 pa1 = *(const short8*)(Psh + (16 * w + lx) * 72 + 32 + q * 8);
#pragma unroll
    for (int s = 0; s < 4; ++s) {
      const short8 vb0 = *(const short8*)(Vsh + (16 * s + lx) * 72 + q * 8);
      const short8 vb1 = *(const short8*)(Vsh + (16 * s + lx) * 72 + 32 + q * 8);
      o[s] = __builtin_amdgcn_mfma_f32_16x16x32_bf16(pa0, vb0, o[s], 0, 0, 0);
      o[s] = __builtin_amdgcn_mfma_f32_16x16x32_bf16(pa1, vb1, o[s], 0, 0, 0);
    }
  }

  // epilogue: O/l -> LDS [i][d] (fp32, pitch 68) -> coalesced store to Ob[b][f][n]
  __syncthreads();
  float* Esh = (float*)(smem + 9216);
#pragma unroll
  for (int r = 0; r < 4; ++r) {
    const float invl = 1.0f / l_r[r];
#pragma unroll
    for (int s = 0; s < 4; ++s)
      Esh[(16 * w + q * 4 + r) * 68 + 16 * s + lx] = o[s][r] * invl;
  }
  __syncthreads();
#pragma unroll
  for (int k = 0; k < 4; ++k) {
    const int e = tid + k * 256;
    const int d = e >> 4;
    const int i4 = (e & 15) * 4;
    float4 v;
    v.x = Esh[(i4 + 0) * 68 + d];
    v.y = Esh[(i4 + 1) * 68 + d];
    v.z = Esh[(i4 + 2) * 68 + d];
    v.w = Esh[(i4 + 3) * 68 + d];
    *(float4*)(Ob + ((size_t)b * FF_ + h * 64 + d) * NTOK_ + i0 + i4) = v;
  }
}

// ---------------------------------------------------------------------------
// Kernel 3: output projection + bias + ReLU + skip -> d_out, + BN stats.
// ---------------------------------------------------------------------------
__global__ __launch_bounds__(256) void proj_kernel(
    const float* __restrict__ Ob, const float* __restrict__ Wo,
    const float* __restrict__ bo, const float* __restrict__ x,
    float* __restrict__ pre, float* __restrict__ stats) {
  __shared__ float Wt[32][68];
  __shared__ float Xt[32][64];
  const int tid = threadIdx.x;
  const int n0 = blockIdx.x * 64;
  const int o0 = blockIdx.y * 64;
  const int b = blockIdx.z;
  const int tx = tid & 15, ty = tid >> 4;
  float acc[4][4];
#pragma unroll
  for (int a = 0; a < 4; ++a)
#pragma unroll
    for (int q = 0; q < 4; ++q) acc[a][q] = 0.f;

  for (int f0 = 0; f0 < FF_; f0 += 32) {
    __syncthreads();
    {
      const int orow = tid >> 3;
      const int cc = (tid & 7) * 4;
#pragma unroll
      for (int p = 0; p < 2; ++p) {
        const int o = p * 32 + orow;
        const float4 w = *(const float4*)(Wo + (size_t)(o0 + o) * FF_ + f0 + cc);
        Wt[cc + 0][o] = w.x; Wt[cc + 1][o] = w.y;
        Wt[cc + 2][o] = w.z; Wt[cc + 3][o] = w.w;
      }
    }
    {
      const int kc = tid >> 3;
      const int nn = (tid & 7) * 8;
      const float* src = Ob + ((size_t)b * FF_ + f0 + kc) * NTOK_ + n0 + nn;
#pragma unroll
      for (int q = 0; q < 2; ++q)
        *(float4*)&Xt[kc][nn + q * 4] = *(const float4*)(src + q * 4);
    }
    __syncthreads();
#pragma unroll
    for (int kc = 0; kc < 32; ++kc) {
      const float4 wv = *(const float4*)&Wt[kc][ty * 4];
      float xv[4];
#pragma unroll
      for (int q = 0; q < 4; ++q) xv[q] = Xt[kc][tx + 16 * q];
      const float wa[4] = {wv.x, wv.y, wv.z, wv.w};
#pragma unroll
      for (int a = 0; a < 4; ++a)
#pragma unroll
        for (int q = 0; q < 4; ++q) acc[a][q] = fmaf(wa[a], xv[q], acc[a][q]);
    }
  }
#pragma unroll
  for (int a = 0; a < 4; ++a) {
    const int o = o0 + ty * 4 + a;
    const float bias = bo[o];
    float s = 0.f, s2 = 0.f;
#pragma unroll
    for (int q = 0; q < 4; ++q) {
      const int n = n0 + tx + 16 * q;
      float v = acc[a][q] + bias;
      v = fmaxf(v, 0.f);
      v += x[((size_t)b * CIN_ + o) * NTOK_ + n];
      pre[((size_t)b * COUT_ + o) * NTOK_ + n] = v;
      s += v;
      s2 += v * v;
    }
#pragma unroll
    for (int off = 1; off < 16; off <<= 1) {
      s += __shfl_down(s, off, 16);
      s2 += __shfl_down(s2, off, 16);
    }
    if (tx == 0) {
      atomicAdd(&stats[o], s);
      atomicAdd(&stats[COUT_ + o], s2);
    }
  }
}

// ---------------------------------------------------------------------------
// Kernel 4: BatchNorm finalize, in place on d_out.
// ---------------------------------------------------------------------------
__global__ __launch_bounds__(256) void bn_kernel(
    float* __restrict__ out, const float* __restrict__ stats,
    const float* __restrict__ gamma, const float* __restrict__ beta) {
  const int idx = blockIdx.x * 256 + threadIdx.x;
  const int e = idx * 4;
  const int c = (e >> 11) & (COUT_ - 1);
  const float inv = 1.0f / (float)(BB_ * NTOK_);
  const float mean = stats[c] * inv;
  const float var = stats[COUT_ + c] * inv - mean * mean;
  const float sc = rsqrtf(var + BNEPS_) * gamma[c];
  const float bt = beta[c];
  float4 v = *(float4*)(out + e);
  v.x = (v.x - mean) * sc + bt;
  v.y = (v.y - mean) * sc + bt;
  v.z = (v.z - mean) * sc + bt;
  v.w = (v.w - mean) * sc + bt;
  *(float4*)(out + e) = v;
}

extern "C" void kernel_launch(void* const* d_in, const int* in_sizes, int n_in,
                              void* d_out, int out_size, void* d_ws, size_t ws_size,
                              hipStream_t stream) {
  (void)in_sizes; (void)n_in; (void)out_size; (void)ws_size;
  const float* x = (const float*)d_in[0];
  const float* WK = (const float*)d_in[1];
  const float* WQ = (const float*)d_in[2];
  const float* WV = (const float*)d_in[3];
  const float* Wo = (const float*)d_in[4];
  const float* bo = (const float*)d_in[5];
  const float* gamma = (const float*)d_in[6];
  const float* beta = (const float*)d_in[7];

  char* ws = (char*)d_ws;
  const size_t BF_SZ = (size_t)BB_ * FF_ * NTOK_ * 2;      // 4 MB per bf16 buf
  unsigned short* Kb = (unsigned short*)(ws);
  unsigned short* Qb = (unsigned short*)(ws + BF_SZ);
  unsigned short* Vt = (unsigned short*)(ws + 2 * BF_SZ);
  float* Obuf = (float*)(ws + 3 * BF_SZ);                  // 8 MB fp32
  float* stats = (float*)(ws + 3 * BF_SZ + (size_t)BB_ * FF_ * NTOK_ * 4);
  float* out = (float*)d_out;

  qkv_kernel<<<dim3(16, 8, 6), 256, 0, stream>>>(x, WK, WQ, WV, Kb, Qb, Vt, stats);
  attn_kernel<<<dim3(512, 1, 1), 256, 0, stream>>>(Kb, Qb, Vt, Obuf);
  proj_kernel<<<dim3(32, 4, 2), 256, 0, stream>>>(Obuf, Wo, bo, x, out, stats);
  bn_kernel<<<1024, 256, 0, stream>>>(out, stats, gamma, beta);
}

// Round 3
// 187.548 us; speedup vs baseline: 2.6281x; 1.2318x over previous
//
#include <hip/hip_runtime.h>
#include <math.h>

#define BB_   2
#define CIN_  256
#define NTOK_ 2048
#define FF_   512
#define COUT_ 256
#define NH_   8
#define DH_   64
#define HW_   128
#define BNEPS_ 1e-5f
#define SCALE_LOG2_ 0.09016844005556021f  /* log2(e)/16 */

typedef __attribute__((ext_vector_type(8))) short short8;
typedef __attribute__((ext_vector_type(4))) float f32x4;

__device__ inline unsigned short f2bf(float f) {
  union { float f; unsigned u; } v; v.f = f;
  unsigned r = (v.u + 0x7FFF + ((v.u >> 16) & 1)) >> 16;  // RNE
  return (unsigned short)r;
}

// ---------------------------------------------------------------------------
// Kernel 0: prep — x fp32 [b][c][n] -> xT bf16 [b][n][c] (LDS transpose);
// weights fp32 -> bf16 flat; zero BN stats.
// Grid: 0..255 x-tiles, 256..383 weight chunks, 384 stats.
// ---------------------------------------------------------------------------
__global__ __launch_bounds__(256) void prep_kernel(
    const float* __restrict__ x, const float* __restrict__ WK,
    const float* __restrict__ WQ, const float* __restrict__ WV,
    const float* __restrict__ Wo, unsigned short* __restrict__ xT,
    unsigned short* __restrict__ Wkb, unsigned short* __restrict__ Wqb,
    unsigned short* __restrict__ Wvb, unsigned short* __restrict__ Wob,
    float* __restrict__ stats) {
  __shared__ float T[64 * 65];  // pitch 65: column reads 2-way (free)
  const int tid = threadIdx.x;
  const int bid = blockIdx.x;
  if (bid < 256) {
    const int b = bid >> 7;
    const int rem = bid & 127;
    const int n0 = (rem >> 2) * 64;
    const int c0 = (rem & 3) * 64;
#pragma unroll
    for (int p = 0; p < 4; ++p) {
      const int idx = tid + 256 * p;
      const int row = idx >> 4, col = (idx & 15) * 4;
      const float4 v =
          *(const float4*)(x + (size_t)(b * CIN_ + c0 + row) * NTOK_ + n0 + col);
      T[row * 65 + col + 0] = v.x; T[row * 65 + col + 1] = v.y;
      T[row * 65 + col + 2] = v.z; T[row * 65 + col + 3] = v.w;
    }
    __syncthreads();
#pragma unroll
    for (int p = 0; p < 2; ++p) {
      const int idx = tid + 256 * p;
      const int nl = idx >> 3, c8 = (idx & 7) * 8;
      unsigned short u[8];
#pragma unroll
      for (int i = 0; i < 8; ++i) u[i] = f2bf(T[(c8 + i) * 65 + nl]);
      *(uint4*)(xT + ((size_t)(b * NTOK_ + n0 + nl)) * CIN_ + c0 + c8) =
          *(uint4*)u;
    }
  } else if (bid < 384) {
    const int t = bid - 256;
    const int which = t >> 5, blk = t & 31;
    const float* src = which == 0 ? WK : which == 1 ? WQ : which == 2 ? WV : Wo;
    unsigned short* dst = which == 0 ? Wkb : which == 1 ? Wqb : which == 2 ? Wvb : Wob;
    const int base = blk * 4096 + tid * 16;
#pragma unroll
    for (int p = 0; p < 4; ++p) {
      const float4 v = *(const float4*)(src + base + p * 4);
      ushort4 u;
      u.x = f2bf(v.x); u.y = f2bf(v.y); u.z = f2bf(v.z); u.w = f2bf(v.w);
      *(ushort4*)(dst + base + p * 4) = u;
    }
  } else {
    for (int i = tid; i < 2 * COUT_; i += 256) stats[i] = 0.f;
  }
}

// ---------------------------------------------------------------------------
// Kernel 1: QKV projection via MFMA. 128f x 128n tile, 4 waves (2x2 quads of
// 64x64), K=256 in 4x64 steps, register-prefetched staging.
// K,Q -> [b][h][n][d] bf16; V (operand-swapped MFMA) -> [b][h][d][n] bf16.
// ---------------------------------------------------------------------------
__global__ __launch_bounds__(256) void qkv_kernel(
    const unsigned short* __restrict__ xT, const unsigned short* __restrict__ Wkb,
    const unsigned short* __restrict__ Wqb, const unsigned short* __restrict__ Wvb,
    unsigned short* __restrict__ Kb, unsigned short* __restrict__ Qb,
    unsigned short* __restrict__ Vt) {
  __shared__ unsigned short Wsh[128 * 72];
  __shared__ unsigned short Xsh[128 * 72];
  const int tid = threadIdx.x;
  const int lane = tid & 63, w = tid >> 6;
  const int lx = lane & 15, q = lane >> 4;
  const int wm = w >> 1, wn = w & 1;
  const int n0 = blockIdx.x * 128;
  const int f0 = blockIdx.y * 128;
  const int b = blockIdx.z / 3, which = blockIdx.z % 3;
  const unsigned short* Wb = which == 0 ? Wkb : which == 1 ? Wqb : Wvb;

  const int srow = tid >> 3;
  const int soff = (tid & 7) * 8;
  const unsigned short* Wg = Wb + (size_t)(f0 + srow) * CIN_ + soff;
  const unsigned short* Xg = xT + ((size_t)(b * NTOK_ + n0 + srow)) * CIN_ + soff;

  uint4 wr[4], xr[4];
#pragma unroll
  for (int r = 0; r < 4; ++r) {
    wr[r] = *(const uint4*)(Wg + (size_t)(32 * r) * CIN_);
    xr[r] = *(const uint4*)(Xg + (size_t)(32 * r) * CIN_);
  }

  f32x4 acc[4][4];
#pragma unroll
  for (int i = 0; i < 4; ++i)
#pragma unroll
    for (int j = 0; j < 4; ++j) acc[i][j] = (f32x4){0.f, 0.f, 0.f, 0.f};

  for (int kk = 0; kk < 4; ++kk) {
    __syncthreads();
#pragma unroll
    for (int r = 0; r < 4; ++r) {
      *(uint4*)(Wsh + (srow + 32 * r) * 72 + soff) = wr[r];
      *(uint4*)(Xsh + (srow + 32 * r) * 72 + soff) = xr[r];
    }
    if (kk < 3) {
      const int c0 = (kk + 1) * 64;
#pragma unroll
      for (int r = 0; r < 4; ++r) {
        wr[r] = *(const uint4*)(Wg + (size_t)(32 * r) * CIN_ + c0);
        xr[r] = *(const uint4*)(Xg + (size_t)(32 * r) * CIN_ + c0);
      }
    }
    __syncthreads();
    short8 wF[4][2], xF[4][2];
#pragma unroll
    for (int i = 0; i < 4; ++i) {
      wF[i][0] = *(const short8*)(Wsh + (64 * wm + 16 * i + lx) * 72 + q * 8);
      wF[i][1] = *(const short8*)(Wsh + (64 * wm + 16 * i + lx) * 72 + 32 + q * 8);
      xF[i][0] = *(const short8*)(Xsh + (64 * wn + 16 * i + lx) * 72 + q * 8);
      xF[i][1] = *(const short8*)(Xsh + (64 * wn + 16 * i + lx) * 72 + 32 + q * 8);
    }
    if (which < 2) {
#pragma unroll
      for (int i = 0; i < 4; ++i)
#pragma unroll
        for (int j = 0; j < 4; ++j) {
          acc[i][j] = __builtin_amdgcn_mfma_f32_16x16x32_bf16(wF[i][0], xF[j][0], acc[i][j], 0, 0, 0);
          acc[i][j] = __builtin_amdgcn_mfma_f32_16x16x32_bf16(wF[i][1], xF[j][1], acc[i][j], 0, 0, 0);
        }
    } else {
#pragma unroll
      for (int i = 0; i < 4; ++i)
#pragma unroll
        for (int j = 0; j < 4; ++j) {
          acc[i][j] = __builtin_amdgcn_mfma_f32_16x16x32_bf16(xF[i][0], wF[j][0], acc[i][j], 0, 0, 0);
          acc[i][j] = __builtin_amdgcn_mfma_f32_16x16x32_bf16(xF[i][1], wF[j][1], acc[i][j], 0, 0, 0);
        }
    }
  }

  const int h = (f0 >> 6) + wm;
  if (which < 2) {
    // D[row=f=16i+4q+r][col=n=16j+lx] -> Y[b][h][n][d], 4 consecutive d
    unsigned short* Y = (which == 0 ? Kb : Qb);
#pragma unroll
    for (int i = 0; i < 4; ++i)
#pragma unroll
      for (int j = 0; j < 4; ++j) {
        const int n = n0 + 64 * wn + 16 * j + lx;
        const int d0 = 16 * i + 4 * q;
        ushort4 u;
        u.x = f2bf(acc[i][j][0]); u.y = f2bf(acc[i][j][1]);
        u.z = f2bf(acc[i][j][2]); u.w = f2bf(acc[i][j][3]);
        *(ushort4*)(Y + ((size_t)((b * NH_ + h) * NTOK_ + n)) * DH_ + d0) = u;
      }
  } else {
    // D[row=n=16i+4q+r][col=f=16j+lx] -> Vt[b][h][d][n], 4 consecutive n
#pragma unroll
    for (int i = 0; i < 4; ++i)
#pragma unroll
      for (int j = 0; j < 4; ++j) {
        const int d = 16 * j + lx;
        const int n = n0 + 64 * wn + 16 * i + 4 * q;
        ushort4 u;
        u.x = f2bf(acc[i][j][0]); u.y = f2bf(acc[i][j][1]);
        u.z = f2bf(acc[i][j][2]); u.w = f2bf(acc[i][j][3]);
        *(ushort4*)(Vt + ((size_t)((b * NH_ + h) * DH_ + d)) * NTOK_ + n) = u;
      }
  }
}

// ---------------------------------------------------------------------------
// Kernel 2: block-causal flash attention via MFMA, register-prefetch pipeline.
// PV computed transposed (A=V^T, B=P^T) so O exits d-row/i-col -> direct bf16
// ushort4 stores into Ob [b][n][f] (proj's B-operand layout).
// ---------------------------------------------------------------------------
__global__ __launch_bounds__(256) void attn_kernel(
    const unsigned short* __restrict__ Kb, const unsigned short* __restrict__ Qb,
    const unsigned short* __restrict__ Vt, unsigned short* __restrict__ Ob) {
  __shared__ __align__(16) char smem[36864];
  unsigned short* Ksh = (unsigned short*)smem;            // [i][d]  64x72
  unsigned short* Qsh = (unsigned short*)(smem + 9216);   // [j][d]  64x72
  unsigned short* Vsh = (unsigned short*)(smem + 18432);  // [d][j]  64x72
  unsigned short* Psh = (unsigned short*)(smem + 27648);  // [i][j]  64x72

  const int tid = threadIdx.x;
  const int lane = tid & 63;
  const int w = tid >> 6;
  const int lx = lane & 15;
  const int q = lane >> 4;

  const int bid = blockIdx.x;  // 0..511, pair heavy with light
  int iblk;
  if (bid < 256) iblk = 31 - (bid >> 4);
  else           iblk = (bid - 256) >> 4;
  const int sub_bh = bid & 15;
  const int h = sub_bh & 7, b = sub_bh >> 3;
  const int i0 = iblk * 64;
  const int njt = ((iblk >> 1) + 1) * 2;

  const size_t bh = (size_t)b * NH_ + h;
  const unsigned short* Kg = Kb + bh * (size_t)NTOK_ * DH_ + (size_t)i0 * DH_;
  const unsigned short* Qg = Qb + bh * (size_t)NTOK_ * DH_;
  const unsigned short* Vg = Vt + bh * (size_t)DH_ * NTOK_;

  const int srow = tid >> 3;          // staging row (+32 per r)
  const int soff = (tid & 7) * 8;

  // stage K tile
#pragma unroll
  for (int r = 0; r < 2; ++r) {
    const int row = srow + 32 * r;
    *(uint4*)(Ksh + row * 72 + soff) = *(const uint4*)(Kg + row * 64 + soff);
  }
  // prefetch jt=0 Q/V into registers
  uint4 qr[2], vr[2];
#pragma unroll
  for (int r = 0; r < 2; ++r) {
    const int row = srow + 32 * r;
    qr[r] = *(const uint4*)(Qg + (size_t)row * 64 + soff);
    vr[r] = *(const uint4*)(Vg + (size_t)row * NTOK_ + soff);
  }
  __syncthreads();

  const short8 aK0 = *(const short8*)(Ksh + (16 * w + lx) * 72 + q * 8);
  const short8 aK1 = *(const short8*)(Ksh + (16 * w + lx) * 72 + 32 + q * 8);

  f32x4 o[4];   // O^T accum: rows d=16s+4q+r, col i=16w+lx
#pragma unroll
  for (int s = 0; s < 4; ++s) o[s] = (f32x4){0.f, 0.f, 0.f, 0.f};
  float m_r[4] = {-1e30f, -1e30f, -1e30f, -1e30f};
  float l_r[4] = {0.f, 0.f, 0.f, 0.f};
  const int gsrc = ((lane & 15) >> 2) << 4;  // stat-owner lane for row lx

  for (int jt = 0; jt < njt; ++jt) {
    __syncthreads();  // previous iteration's LDS reads complete
#pragma unroll
    for (int r = 0; r < 2; ++r) {
      const int row = srow + 32 * r;
      *(uint4*)(Qsh + row * 72 + soff) = qr[r];
      *(uint4*)(Vsh + row * 72 + soff) = vr[r];
    }
    if (jt + 1 < njt) {
      const int j0n = (jt + 1) * 64;
#pragma unroll
      for (int r = 0; r < 2; ++r) {
        const int row = srow + 32 * r;
        qr[r] = *(const uint4*)(Qg + (size_t)(j0n + row) * 64 + soff);
        vr[r] = *(const uint4*)(Vg + (size_t)row * NTOK_ + j0n + soff);
      }
    }
    __syncthreads();

    // S-phase: S[16i x 64j] per wave (rows i=16w+4q+r, col j=16s+lx)
    f32x4 sa[4];
#pragma unroll
    for (int s = 0; s < 4; ++s) {
      sa[s] = (f32x4){0.f, 0.f, 0.f, 0.f};
      const short8 b0 = *(const short8*)(Qsh + (16 * s + lx) * 72 + q * 8);
      const short8 b1 = *(const short8*)(Qsh + (16 * s + lx) * 72 + 32 + q * 8);
      sa[s] = __builtin_amdgcn_mfma_f32_16x16x32_bf16(aK0, b0, sa[s], 0, 0, 0);
      sa[s] = __builtin_amdgcn_mfma_f32_16x16x32_bf16(aK1, b1, sa[s], 0, 0, 0);
    }

    // online softmax (exp2 domain), stats per reg-row 4q+r
    float vmax[4];
#pragma unroll
    for (int r = 0; r < 4; ++r) {
      float m0 = fmaxf(fmaxf(sa[0][r], sa[1][r]), fmaxf(sa[2][r], sa[3][r]));
      m0 *= SCALE_LOG2_;
#pragma unroll
      for (int off = 1; off < 16; off <<= 1)
        m0 = fmaxf(m0, __shfl_xor(m0, off));
      vmax[r] = m0;
    }
    float corr[4], rs[4];
#pragma unroll
    for (int r = 0; r < 4; ++r) {
      const float mn = fmaxf(m_r[r], vmax[r]);
      corr[r] = __builtin_amdgcn_exp2f(m_r[r] - mn);
      m_r[r] = mn;
      rs[r] = 0.f;
    }
    unsigned short pbf[4][4];
#pragma unroll
    for (int s = 0; s < 4; ++s)
#pragma unroll
      for (int r = 0; r < 4; ++r) {
        const float p = __builtin_amdgcn_exp2f(sa[s][r] * SCALE_LOG2_ - m_r[r]);
        pbf[s][r] = f2bf(p);
        rs[r] += p;
      }
#pragma unroll
    for (int r = 0; r < 4; ++r) {
#pragma unroll
      for (int off = 1; off < 16; off <<= 1) rs[r] += __shfl_xor(rs[r], off);
      l_r[r] = l_r[r] * corr[r] + rs[r];
    }
    // per-lane correction for O columns (col i = lx)
    const float t0 = __shfl(corr[0], gsrc);
    const float t1 = __shfl(corr[1], gsrc);
    const float t2 = __shfl(corr[2], gsrc);
    const float t3 = __shfl(corr[3], gsrc);
    const float cO = (lx & 2) ? ((lx & 1) ? t3 : t2) : ((lx & 1) ? t1 : t0);
#pragma unroll
    for (int s = 0; s < 4; ++s) {
      o[s] *= cO;
#pragma unroll
      for (int r = 0; r < 4; ++r)
        Psh[(16 * w + q * 4 + r) * 72 + 16 * s + lx] = pbf[s][r];
    }
    asm volatile("s_waitcnt lgkmcnt(0)" ::: "memory");  // own-wave P visible

    // PV^T: O^T[64d x 16i] += V^T[64d x 64j] * P^T[64j x 16i]
    const short8 pb0 = *(const short8*)(Psh + (16 * w + lx) * 72 + q * 8);
    const short8 pb1 = *(const short8*)(Psh + (16 * w + lx) * 72 + 32 + q * 8);
#pragma unroll
    for (int s = 0; s < 4; ++s) {
      const short8 va0 = *(const short8*)(Vsh + (16 * s + lx) * 72 + q * 8);
      const short8 va1 = *(const short8*)(Vsh + (16 * s + lx) * 72 + 32 + q * 8);
      o[s] = __builtin_amdgcn_mfma_f32_16x16x32_bf16(va0, pb0, o[s], 0, 0, 0);
      o[s] = __builtin_amdgcn_mfma_f32_16x16x32_bf16(va1, pb1, o[s], 0, 0, 0);
    }
  }

  // epilogue: per-lane 1/l for row i=16w+lx, direct bf16 stores to Ob[b][n][f]
  const float u0 = __shfl(l_r[0], gsrc);
  const float u1 = __shfl(l_r[1], gsrc);
  const float u2 = __shfl(l_r[2], gsrc);
  const float u3 = __shfl(l_r[3], gsrc);
  const float lsel = (lx & 2) ? ((lx & 1) ? u3 : u2) : ((lx & 1) ? u1 : u0);
  const float invl = 1.0f / lsel;
  const int n = i0 + 16 * w + lx;
#pragma unroll
  for (int s = 0; s < 4; ++s) {
    ushort4 u;
    u.x = f2bf(o[s][0] * invl); u.y = f2bf(o[s][1] * invl);
    u.z = f2bf(o[s][2] * invl); u.w = f2bf(o[s][3] * invl);
    *(ushort4*)(Ob + ((size_t)(b * NTOK_ + n)) * FF_ + h * 64 + 16 * s + 4 * q) = u;
  }
}

// ---------------------------------------------------------------------------
// Kernel 3: output projection via MFMA (A=Ob rows n, B=Wo rows o) + bias +
// ReLU + skip -> d_out fp32 [b][o][n], + BN stats (shuffle-reduced atomics).
// 64n x 64o tile, 4 waves (2x2 quads of 32x32), K=512 in 8x64 steps.
// ---------------------------------------------------------------------------
__global__ __launch_bounds__(256) void proj_kernel(
    const unsigned short* __restrict__ Ob, const unsigned short* __restrict__ Wob,
    const float* __restrict__ bo, const float* __restrict__ x,
    float* __restrict__ pre, float* __restrict__ stats) {
  __shared__ unsigned short Osh[64 * 72];
  __shared__ unsigned short Wsh[64 * 72];
  const int tid = threadIdx.x;
  const int lane = tid & 63, w = tid >> 6;
  const int lx = lane & 15, q = lane >> 4;
  const int wn = w & 1, wo = w >> 1;
  const int n0 = blockIdx.x * 64;
  const int o0 = blockIdx.y * 64;
  const int b = blockIdx.z;

  const int srow = tid >> 3;
  const int soff = (tid & 7) * 8;
  const unsigned short* Og = Ob + ((size_t)(b * NTOK_ + n0 + srow)) * FF_ + soff;
  const unsigned short* Wg = Wob + (size_t)(o0 + srow) * FF_ + soff;

  uint4 orr[2], wrr[2];
#pragma unroll
  for (int r = 0; r < 2; ++r) {
    orr[r] = *(const uint4*)(Og + (size_t)(32 * r) * FF_);
    wrr[r] = *(const uint4*)(Wg + (size_t)(32 * r) * FF_);
  }

  f32x4 acc[2][2];
#pragma unroll
  for (int i = 0; i < 2; ++i)
#pragma unroll
    for (int j = 0; j < 2; ++j) acc[i][j] = (f32x4){0.f, 0.f, 0.f, 0.f};

  for (int kk = 0; kk < 8; ++kk) {
    __syncthreads();
#pragma unroll
    for (int r = 0; r < 2; ++r) {
      *(uint4*)(Osh + (srow + 32 * r) * 72 + soff) = orr[r];
      *(uint4*)(Wsh + (srow + 32 * r) * 72 + soff) = wrr[r];
    }
    if (kk < 7) {
      const int c0 = (kk + 1) * 64;
#pragma unroll
      for (int r = 0; r < 2; ++r) {
        orr[r] = *(const uint4*)(Og + (size_t)(32 * r) * FF_ + c0);
        wrr[r] = *(const uint4*)(Wg + (size_t)(32 * r) * FF_ + c0);
      }
    }
    __syncthreads();
    short8 aF[2][2], bF[2][2];
#pragma unroll
    for (int i = 0; i < 2; ++i) {
      aF[i][0] = *(const short8*)(Osh + (32 * wn + 16 * i + lx) * 72 + q * 8);
      aF[i][1] = *(const short8*)(Osh + (32 * wn + 16 * i + lx) * 72 + 32 + q * 8);
      bF[i][0] = *(const short8*)(Wsh + (32 * wo + 16 * i + lx) * 72 + q * 8);
      bF[i][1] = *(const short8*)(Wsh + (32 * wo + 16 * i + lx) * 72 + 32 + q * 8);
    }
#pragma unroll
    for (int i = 0; i < 2; ++i)
#pragma unroll
      for (int j = 0; j < 2; ++j) {
        acc[i][j] = __builtin_amdgcn_mfma_f32_16x16x32_bf16(aF[i][0], bF[j][0], acc[i][j], 0, 0, 0);
        acc[i][j] = __builtin_amdgcn_mfma_f32_16x16x32_bf16(aF[i][1], bF[j][1], acc[i][j], 0, 0, 0);
      }
  }

  // epilogue: D[row=n=16i+4q+r][col=o=16j+lx]
  float s[2] = {0.f, 0.f}, s2[2] = {0.f, 0.f};
#pragma unroll
  for (int j = 0; j < 2; ++j) {
    const int o = o0 + 32 * wo + 16 * j + lx;
    const float bias = bo[o];
#pragma unroll
    for (int i = 0; i < 2; ++i) {
      const int n = n0 + 32 * wn + 16 * i + 4 * q;
      const float4 xv = *(const float4*)(x + ((size_t)(b * CIN_ + o)) * NTOK_ + n);
      float4 v;
      v.x = fmaxf(acc[i][j][0] + bias, 0.f) + xv.x;
      v.y = fmaxf(acc[i][j][1] + bias, 0.f) + xv.y;
      v.z = fmaxf(acc[i][j][2] + bias, 0.f) + xv.z;
      v.w = fmaxf(acc[i][j][3] + bias, 0.f) + xv.w;
      *(float4*)(pre + ((size_t)(b * COUT_ + o)) * NTOK_ + n) = v;
      s[j] += v.x + v.y + v.z + v.w;
      s2[j] += v.x * v.x + v.y * v.y + v.z * v.z + v.w * v.w;
    }
  }
#pragma unroll
  for (int j = 0; j < 2; ++j) {
    s[j] += __shfl_xor(s[j], 16);  s[j] += __shfl_xor(s[j], 32);
    s2[j] += __shfl_xor(s2[j], 16); s2[j] += __shfl_xor(s2[j], 32);
  }
  if (lane < 16) {
#pragma unroll
    for (int j = 0; j < 2; ++j) {
      const int o = o0 + 32 * wo + 16 * j + lx;
      atomicAdd(&stats[o], s[j]);
      atomicAdd(&stats[COUT_ + o], s2[j]);
    }
  }
}

// ---------------------------------------------------------------------------
// Kernel 4: BatchNorm finalize, in place on d_out.
// ---------------------------------------------------------------------------
__global__ __launch_bounds__(256) void bn_kernel(
    float* __restrict__ out, const float* __restrict__ stats,
    const float* __restrict__ gamma, const float* __restrict__ beta) {
  const int idx = blockIdx.x * 256 + threadIdx.x;
  const int e = idx * 4;
  const int c = (e >> 11) & (COUT_ - 1);
  const float inv = 1.0f / (float)(BB_ * NTOK_);
  const float mean = stats[c] * inv;
  const float var = stats[COUT_ + c] * inv - mean * mean;
  const float sc = rsqrtf(var + BNEPS_) * gamma[c];
  const float bt = beta[c];
  float4 v = *(float4*)(out + e);
  v.x = (v.x - mean) * sc + bt;
  v.y = (v.y - mean) * sc + bt;
  v.z = (v.z - mean) * sc + bt;
  v.w = (v.w - mean) * sc + bt;
  *(float4*)(out + e) = v;
}

extern "C" void kernel_launch(void* const* d_in, const int* in_sizes, int n_in,
                              void* d_out, int out_size, void* d_ws, size_t ws_size,
                              hipStream_t stream) {
  (void)in_sizes; (void)n_in; (void)out_size; (void)ws_size;
  const float* x = (const float*)d_in[0];
  const float* WK = (const float*)d_in[1];
  const float* WQ = (const float*)d_in[2];
  const float* WV = (const float*)d_in[3];
  const float* Wo = (const float*)d_in[4];
  const float* bo = (const float*)d_in[5];
  const float* gamma = (const float*)d_in[6];
  const float* beta = (const float*)d_in[7];

  char* ws = (char*)d_ws;
  unsigned short* xT  = (unsigned short*)(ws);                    // 2 MB
  unsigned short* Wkb = (unsigned short*)(ws + 2097152);          // 256 KB
  unsigned short* Wqb = (unsigned short*)(ws + 2359296);
  unsigned short* Wvb = (unsigned short*)(ws + 2621440);
  unsigned short* Wob = (unsigned short*)(ws + 2883584);
  unsigned short* Kb  = (unsigned short*)(ws + 3145728);          // 4 MB
  unsigned short* Qb  = (unsigned short*)(ws + 7340032);
  unsigned short* Vt  = (unsigned short*)(ws + 11534336);
  unsigned short* Ob  = (unsigned short*)(ws + 15728640);         // 4 MB
  float* stats        = (float*)(ws + 19922944);                  // 2 KB
  float* out = (float*)d_out;

  prep_kernel<<<385, 256, 0, stream>>>(x, WK, WQ, WV, Wo, xT, Wkb, Wqb, Wvb, Wob, stats);
  qkv_kernel<<<dim3(16, 4, 6), 256, 0, stream>>>(xT, Wkb, Wqb, Wvb, Kb, Qb, Vt);
  attn_kernel<<<dim3(512, 1, 1), 256, 0, stream>>>(Kb, Qb, Vt, Ob);
  proj_kernel<<<dim3(32, 4, 2), 256, 0, stream>>>(Ob, Wob, bo, x, out, stats);
  bn_kernel<<<1024, 256, 0, stream>>>(out, stats, gamma, beta);
}